// Round 3
// baseline (253.667 us; speedup 1.0000x reference)
//
#include <hip/hip_runtime.h>

// EAConv: EM-routing neighbor aggregation + temporal blend, FULLY FUSED.
// T=3, b=1, n=50000, d=64, m=16, K=4, dd=16.
// R9 changes vs R8:
//  - ONE kernel: wave = node i; loop t=0..2 inside; temporal blend done in
//    registers (combine kernel + its launch gap + 64MB traffic eliminated).
//  - Coalesced gather: instr c loads neighbor rows 4c..4c+3 IN FULL
//    (64 lanes x 16B = 4 rows x 256B, 16 cache lines/instr instead of 64,
//    each line touched once instead of 4x) -> 4x fewer TA/L1 transactions.
//    A 4KB/wave LDS transpose (XOR-swizzled 16B granules, bank-floor) then
//    hands lane (k,m) its z[m][k*16..+15] fragment. z re-reads (if the
//    compiler still wants low pressure) now hit LDS, not the TA.
//  - Next-iter logit dot fused into each update sweep (removes the two
//    standalone 16-FMA dot passes).
// Lane = (k,m): m=lane&15 neighbor, k=lane>>4 factor.

constexpr int T  = 3;
constexpr int N  = 50000;
constexpr int D  = 64;
constexpr int M  = 16;
constexpr int DD = 16;
constexpr float EPS2 = 1e-24f;  // (1e-12)^2

template <int CTRL>
__device__ __forceinline__ float dpp_add(float v) {
    // mov_dpp with undef old -> GCNDPPCombine can fuse into v_add_f32_dpp
    int rot = __builtin_amdgcn_mov_dpp(__float_as_int(v), CTRL, 0xF, 0xF, false);
    return v + __int_as_float(rot);
}
// sum over the 16 lanes of a row; result broadcast to every lane of the row
__device__ __forceinline__ float rowsum16(float v) {
    v = dpp_add<0x128>(v);  // row_ror:8
    v = dpp_add<0x124>(v);  // row_ror:4
    v = dpp_add<0x122>(v);  // row_ror:2
    v = dpp_add<0x121>(v);  // row_ror:1
    return v;
}

__global__ __launch_bounds__(256, 4) void eaconv_fused(
    const float* __restrict__ x_all,   // [T,N,D]
    const int*   __restrict__ nbr_all, // [T,N,M]
    float*       __restrict__ out)     // [T,N,D] <- final blended embeddings
{
    __shared__ float zb[4][M * D];     // 4 KB per wave, 16 KB per block
    const int wv   = threadIdx.x >> 6;
    const int i    = blockIdx.x * 4 + wv;
    const int lane = threadIdx.x & 63;
    if (i >= N) return;
    const int m  = lane & 15;
    const int k  = lane >> 4;
    const int x7 = m & 7;
    float* zw = zb[wv];

    float acc[DD];                       // temporal-blend carry
    const float s1q = 0.25f * 0.7310585786300049f;  // 0.25*sigmoid(1)

#pragma unroll
    for (int t = 0; t < T; ++t) {
        const float* x = x_all + (size_t)t * N * D;
        int j = nbr_all[((size_t)t * N + i) * M + m];
        const bool valid = (unsigned)j < (unsigned)N;
        j = valid ? j : 0;

        // ---- coalesced gather: 4 instrs, each loads 4 full neighbor rows.
        // lane (k,m) fetches 16B at row j_{4c+k}, dims [4m..4m+3], and stores
        // it to LDS row (4c+k), granule slot m ^ (row&7)  (bank-floor swizzle).
#pragma unroll
        for (int c = 0; c < 4; ++c) {
            const int mm = 4 * c + k;
            const int jr = __shfl(j, mm, 64);
            const float4 v = *(const float4*)(x + (size_t)jr * D + m * 4);
            *(float4*)&zw[mm * 64 + ((m ^ (mm & 7)) << 2)] = v;
        }

        // ---- own row (wave-broadcast addresses, cheap) ----
        const float4* xr = (const float4*)(x + (size_t)i * D + k * DD);
        float4 a0 = xr[0], a1 = xr[1], a2 = xr[2], a3 = xr[3];
        float xk[DD] = {a0.x,a0.y,a0.z,a0.w, a1.x,a1.y,a1.z,a1.w,
                        a2.x,a2.y,a2.z,a2.w, a3.x,a3.y,a3.z,a3.w};

        // ---- transpose readback: z[p] = x[j_m][k*16+p] ----
        float z[DD];
#pragma unroll
        for (int q = 0; q < 4; ++q) {
            const float4 v =
                *(const float4*)&zw[m * 64 + (((4 * k + q) ^ x7) << 2)];
            z[4*q+0] = v.x; z[4*q+1] = v.y; z[4*q+2] = v.z; z[4*q+3] = v.w;
        }

        // ---- norms: xk normalized in place; z stays raw, 1/||z|| -> rz ----
        float sxp0 = xk[0]*xk[0], sxp1 = xk[1]*xk[1],
              sxp2 = xk[2]*xk[2], sxp3 = xk[3]*xk[3];
        float szp0 = z[0]*z[0],   szp1 = z[1]*z[1],
              szp2 = z[2]*z[2],   szp3 = z[3]*z[3];
#pragma unroll
        for (int p = 4; p < DD; p += 4) {
            sxp0 = fmaf(xk[p+0], xk[p+0], sxp0);
            sxp1 = fmaf(xk[p+1], xk[p+1], sxp1);
            sxp2 = fmaf(xk[p+2], xk[p+2], sxp2);
            sxp3 = fmaf(xk[p+3], xk[p+3], sxp3);
            szp0 = fmaf(z[p+0],  z[p+0],  szp0);
            szp1 = fmaf(z[p+1],  z[p+1],  szp1);
            szp2 = fmaf(z[p+2],  z[p+2],  szp2);
            szp3 = fmaf(z[p+3],  z[p+3],  szp3);
        }
        const float sx = (sxp0 + sxp1) + (sxp2 + sxp3);
        const float sz = (szp0 + szp1) + (szp2 + szp3);
        const float rx = __builtin_amdgcn_rsqf(fmaxf(sx, EPS2));
        float rz = __builtin_amdgcn_rsqf(fmaxf(sz, EPS2));
        if (!valid) rz = 0.f;
#pragma unroll
        for (int p = 0; p < DD; ++p) xk[p] *= rx;

        // ---- iter 0: u = sum_m rz_m*z_m + 4*xk (direction only) ----
        //      fused: dot1 = z . u  for iter 1's logit
        float u[DD];
        float d0 = 0.f, d1 = 0.f, d2 = 0.f, d3 = 0.f;
#pragma unroll
        for (int p = 0; p < DD; p += 4) {
            u[p+0] = fmaf(xk[p+0], 4.0f, rowsum16(z[p+0] * rz));
            u[p+1] = fmaf(xk[p+1], 4.0f, rowsum16(z[p+1] * rz));
            u[p+2] = fmaf(xk[p+2], 4.0f, rowsum16(z[p+2] * rz));
            u[p+3] = fmaf(xk[p+3], 4.0f, rowsum16(z[p+3] * rz));
            d0 = fmaf(z[p+0], u[p+0], d0);
            d1 = fmaf(z[p+1], u[p+1], d1);
            d2 = fmaf(z[p+2], u[p+2], d2);
            d3 = fmaf(z[p+3], u[p+3], d3);
        }
        float np0 = u[0]*u[0], np1 = u[1]*u[1], np2 = u[2]*u[2], np3 = u[3]*u[3];
#pragma unroll
        for (int p = 4; p < DD; p += 4) {
            np0 = fmaf(u[p+0], u[p+0], np0);
            np1 = fmaf(u[p+1], u[p+1], np1);
            np2 = fmaf(u[p+2], u[p+2], np2);
            np3 = fmaf(u[p+3], u[p+3], np3);
        }
        float inv = __builtin_amdgcn_rsqf(fmaxf((np0+np1)+(np2+np3), EPS2));
        float dot = (d0 + d1) + (d2 + d3);

        // ---- iters 1..2 ----
#pragma unroll
        for (int it = 1; it < 3; ++it) {
            const float logit = dot * (rz * inv);  // zhat . uhat, in [-1,1]
            const float e = __expf(logit);
            float es = e + __shfl_xor(e, 16, 64);  // softmax denom over k
            es += __shfl_xor(es, 32, 64);
            const float wf = e * __builtin_amdgcn_rcpf(es) * rz;
            float e0 = 0.f, e1 = 0.f, e2 = 0.f, e3 = 0.f;
#pragma unroll
            for (int p = 0; p < DD; p += 4) {
                u[p+0] = xk[p+0] + rowsum16(z[p+0] * wf);
                u[p+1] = xk[p+1] + rowsum16(z[p+1] * wf);
                u[p+2] = xk[p+2] + rowsum16(z[p+2] * wf);
                u[p+3] = xk[p+3] + rowsum16(z[p+3] * wf);
                e0 = fmaf(z[p+0], u[p+0], e0);
                e1 = fmaf(z[p+1], u[p+1], e1);
                e2 = fmaf(z[p+2], u[p+2], e2);
                e3 = fmaf(z[p+3], u[p+3], e3);
            }
            if (it < 2) {
                dot = (e0 + e1) + (e2 + e3);
                float a0n = u[0]*u[0], a1n = u[1]*u[1],
                      a2n = u[2]*u[2], a3n = u[3]*u[3];
#pragma unroll
                for (int p = 4; p < DD; p += 4) {
                    a0n = fmaf(u[p+0], u[p+0], a0n);
                    a1n = fmaf(u[p+1], u[p+1], a1n);
                    a2n = fmaf(u[p+2], u[p+2], a2n);
                    a3n = fmaf(u[p+3], u[p+3], a3n);
                }
                inv = __builtin_amdgcn_rsqf(fmaxf((a0n+a1n)+(a2n+a3n), EPS2));
            }
        }

        // ---- temporal blend (in registers) + store ----
        float w[DD];
        if (t == 0) {
#pragma unroll
            for (int p = 0; p < DD; ++p) { w[p] = u[p]; acc[p] = u[p]; }
        } else if (t == 1) {
#pragma unroll
            for (int p = 0; p < DD; ++p) {
                w[p] = 0.25f * acc[p] + 0.5f * u[p];          // e1
                acc[p] = fmaf(s1q, w[p], 0.125f * acc[p]);    // carry for e2
            }
        } else {
#pragma unroll
            for (int p = 0; p < DD; ++p) w[p] = acc[p] + 0.5f * u[p];  // e2
        }
        float* o = out + ((size_t)t * N + i) * D + k * DD;
        if (m == 0) ((float4*)o)[0] = make_float4(w[0],  w[1],  w[2],  w[3]);
        if (m == 1) ((float4*)o)[1] = make_float4(w[4],  w[5],  w[6],  w[7]);
        if (m == 2) ((float4*)o)[2] = make_float4(w[8],  w[9],  w[10], w[11]);
        if (m == 3) ((float4*)o)[3] = make_float4(w[12], w[13], w[14], w[15]);
    }
}

extern "C" void kernel_launch(void* const* d_in, const int* in_sizes, int n_in,
                              void* d_out, int out_size, void* d_ws, size_t ws_size,
                              hipStream_t stream) {
    const float* x_all = (const float*)d_in[0];
    const int*   nbrs  = (const int*)d_in[1];
    float*       out   = (float*)d_out;

    // one wave per node, 4 waves per block
    const int blocks = (N + 3) / 4;  // 12500
    eaconv_fused<<<blocks, 256, 0, stream>>>(x_all, nbrs, out);
}

// Round 4
// 240.662 us; speedup vs baseline: 1.0540x; 1.0540x over previous
//
#include <hip/hip_runtime.h>

// EAConv: EM-routing neighbor aggregation + temporal blend, FULLY FUSED.
// T=3, b=1, n=50000, d=64, m=16, K=4, dd=16.
// R10 = R9 minus the register-pressure spill:
//  - R9 spilled (~76 MB scratch writes + ~80 MB scratch reads visible in
//    WRITE_SIZE/FETCH_SIZE) because xk+z+u+acc ~= 85 live floats vs a
//    64-VGPR allocation. Fix: z is NOT kept in registers; every sweep
//    re-reads it from the wave-private LDS transpose buffer one float4 at
//    a time (ds_read_b128, ~12cy, off critical path). Live state drops to
//    xk[16]+u[16]+acc[16]+window+partials ~= 70.
//  - __launch_bounds__(256, 3): VGPR budget ~170 so the allocator never
//    prefers scratch. R8 proved occupancy-insensitivity down to ~40%.
//  - Everything else identical to R9 (verified PASSED): coalesced gather
//    (4 instrs x 4 full rows, 64 line-transactions/wave-t vs 265 scattered),
//    XOR-swizzled 16B-granule LDS transpose, fused next-iter dot,
//    in-register temporal blend, single dispatch.
// Lane = (k,m): m=lane&15 neighbor, k=lane>>4 factor.

constexpr int T  = 3;
constexpr int N  = 50000;
constexpr int D  = 64;
constexpr int M  = 16;
constexpr int DD = 16;
constexpr float EPS2 = 1e-24f;  // (1e-12)^2

template <int CTRL>
__device__ __forceinline__ float dpp_add(float v) {
    // mov_dpp with undef old -> GCNDPPCombine can fuse into v_add_f32_dpp
    int rot = __builtin_amdgcn_mov_dpp(__float_as_int(v), CTRL, 0xF, 0xF, false);
    return v + __int_as_float(rot);
}
// sum over the 16 lanes of a row; result broadcast to every lane of the row
__device__ __forceinline__ float rowsum16(float v) {
    v = dpp_add<0x128>(v);  // row_ror:8
    v = dpp_add<0x124>(v);  // row_ror:4
    v = dpp_add<0x122>(v);  // row_ror:2
    v = dpp_add<0x121>(v);  // row_ror:1
    return v;
}

__global__ __launch_bounds__(256, 3) void eaconv_fused(
    const float* __restrict__ x_all,   // [T,N,D]
    const int*   __restrict__ nbr_all, // [T,N,M]
    float*       __restrict__ out)     // [T,N,D] <- final blended embeddings
{
    __shared__ float zb[4][M * D];     // 4 KB per wave, 16 KB per block
    const int wv   = threadIdx.x >> 6;
    const int i    = blockIdx.x * 4 + wv;
    const int lane = threadIdx.x & 63;
    if (i >= N) return;
    const int m  = lane & 15;
    const int k  = lane >> 4;
    const int x7 = m & 7;
    float* zw = zb[wv];

    float acc[DD];                       // temporal-blend carry
    const float s1q = 0.25f * 0.7310585786300049f;  // 0.25*sigmoid(1)

    // z readback window: row m, granule (4k+q) -> dims [16k+4q .. +3]
#define LDSQ(q) (*(const float4*)&zw[m * 64 + (((4 * k + (q)) ^ x7) << 2)])

#pragma unroll
    for (int t = 0; t < T; ++t) {
        const float* x = x_all + (size_t)t * N * D;
        int j = nbr_all[((size_t)t * N + i) * M + m];
        const bool valid = (unsigned)j < (unsigned)N;
        j = valid ? j : 0;

        // ---- coalesced gather: 4 instrs, each loads 4 full neighbor rows.
        // lane (k,m) fetches 16B at row j_{4c+k}, dims [4m..4m+3], stores to
        // LDS row (4c+k), granule slot m ^ (row&7)  (bank-floor swizzle).
#pragma unroll
        for (int c = 0; c < 4; ++c) {
            const int mm = 4 * c + k;
            const int jr = __shfl(j, mm, 64);
            const float4 v = *(const float4*)(x + (size_t)jr * D + m * 4);
            *(float4*)&zw[mm * 64 + ((m ^ (mm & 7)) << 2)] = v;
        }

        // ---- own row (wave-broadcast addresses, cheap) ----
        const float4* xr = (const float4*)(x + (size_t)i * D + k * DD);
        float4 a0 = xr[0], a1 = xr[1], a2 = xr[2], a3 = xr[3];
        float xk[DD] = {a0.x,a0.y,a0.z,a0.w, a1.x,a1.y,a1.z,a1.w,
                        a2.x,a2.y,a2.z,a2.w, a3.x,a3.y,a3.z,a3.w};

        // ---- norms: xk normalized in place; ||z|| from LDS windows ----
        float sxp0 = xk[0]*xk[0], sxp1 = xk[1]*xk[1],
              sxp2 = xk[2]*xk[2], sxp3 = xk[3]*xk[3];
#pragma unroll
        for (int p = 4; p < DD; p += 4) {
            sxp0 = fmaf(xk[p+0], xk[p+0], sxp0);
            sxp1 = fmaf(xk[p+1], xk[p+1], sxp1);
            sxp2 = fmaf(xk[p+2], xk[p+2], sxp2);
            sxp3 = fmaf(xk[p+3], xk[p+3], sxp3);
        }
        float szp0 = 0.f, szp1 = 0.f, szp2 = 0.f, szp3 = 0.f;
#pragma unroll
        for (int q = 0; q < 4; ++q) {
            const float4 zq = LDSQ(q);
            szp0 = fmaf(zq.x, zq.x, szp0);
            szp1 = fmaf(zq.y, zq.y, szp1);
            szp2 = fmaf(zq.z, zq.z, szp2);
            szp3 = fmaf(zq.w, zq.w, szp3);
        }
        const float sx = (sxp0 + sxp1) + (sxp2 + sxp3);
        const float sz = (szp0 + szp1) + (szp2 + szp3);
        const float rx = __builtin_amdgcn_rsqf(fmaxf(sx, EPS2));
        float rz = __builtin_amdgcn_rsqf(fmaxf(sz, EPS2));
        if (!valid) rz = 0.f;
#pragma unroll
        for (int p = 0; p < DD; ++p) xk[p] *= rx;

        // ---- iter 0: u = sum_m rz_m*z_m + 4*xk (direction only) ----
        //      fused: dot = z . u  for iter 1's logit
        float u[DD];
        float d0 = 0.f, d1 = 0.f, d2 = 0.f, d3 = 0.f;
#pragma unroll
        for (int q = 0; q < 4; ++q) {
            const float4 zq = LDSQ(q);
            const int p = 4 * q;
            u[p+0] = fmaf(xk[p+0], 4.0f, rowsum16(zq.x * rz));
            u[p+1] = fmaf(xk[p+1], 4.0f, rowsum16(zq.y * rz));
            u[p+2] = fmaf(xk[p+2], 4.0f, rowsum16(zq.z * rz));
            u[p+3] = fmaf(xk[p+3], 4.0f, rowsum16(zq.w * rz));
            d0 = fmaf(zq.x, u[p+0], d0);
            d1 = fmaf(zq.y, u[p+1], d1);
            d2 = fmaf(zq.z, u[p+2], d2);
            d3 = fmaf(zq.w, u[p+3], d3);
        }
        float np0 = u[0]*u[0], np1 = u[1]*u[1], np2 = u[2]*u[2], np3 = u[3]*u[3];
#pragma unroll
        for (int p = 4; p < DD; p += 4) {
            np0 = fmaf(u[p+0], u[p+0], np0);
            np1 = fmaf(u[p+1], u[p+1], np1);
            np2 = fmaf(u[p+2], u[p+2], np2);
            np3 = fmaf(u[p+3], u[p+3], np3);
        }
        float inv = __builtin_amdgcn_rsqf(fmaxf((np0+np1)+(np2+np3), EPS2));
        float dot = (d0 + d1) + (d2 + d3);

        // ---- iters 1..2 ----
#pragma unroll
        for (int it = 1; it < 3; ++it) {
            const float logit = dot * (rz * inv);  // zhat . uhat, in [-1,1]
            const float e = __expf(logit);
            float es = e + __shfl_xor(e, 16, 64);  // softmax denom over k
            es += __shfl_xor(es, 32, 64);
            const float wf = e * __builtin_amdgcn_rcpf(es) * rz;
            float e0 = 0.f, e1 = 0.f, e2 = 0.f, e3 = 0.f;
#pragma unroll
            for (int q = 0; q < 4; ++q) {
                const float4 zq = LDSQ(q);
                const int p = 4 * q;
                u[p+0] = xk[p+0] + rowsum16(zq.x * wf);
                u[p+1] = xk[p+1] + rowsum16(zq.y * wf);
                u[p+2] = xk[p+2] + rowsum16(zq.z * wf);
                u[p+3] = xk[p+3] + rowsum16(zq.w * wf);
                e0 = fmaf(zq.x, u[p+0], e0);
                e1 = fmaf(zq.y, u[p+1], e1);
                e2 = fmaf(zq.z, u[p+2], e2);
                e3 = fmaf(zq.w, u[p+3], e3);
            }
            if (it < 2) {
                dot = (e0 + e1) + (e2 + e3);
                float a0n = u[0]*u[0], a1n = u[1]*u[1],
                      a2n = u[2]*u[2], a3n = u[3]*u[3];
#pragma unroll
                for (int p = 4; p < DD; p += 4) {
                    a0n = fmaf(u[p+0], u[p+0], a0n);
                    a1n = fmaf(u[p+1], u[p+1], a1n);
                    a2n = fmaf(u[p+2], u[p+2], a2n);
                    a3n = fmaf(u[p+3], u[p+3], a3n);
                }
                inv = __builtin_amdgcn_rsqf(fmaxf((a0n+a1n)+(a2n+a3n), EPS2));
            }
        }

        // ---- temporal blend (in registers) + store ----
        float w[DD];
        if (t == 0) {
#pragma unroll
            for (int p = 0; p < DD; ++p) { w[p] = u[p]; acc[p] = u[p]; }
        } else if (t == 1) {
#pragma unroll
            for (int p = 0; p < DD; ++p) {
                w[p] = 0.25f * acc[p] + 0.5f * u[p];          // e1
                acc[p] = fmaf(s1q, w[p], 0.125f * acc[p]);    // carry for e2
            }
        } else {
#pragma unroll
            for (int p = 0; p < DD; ++p) w[p] = acc[p] + 0.5f * u[p];  // e2
        }
        float* o = out + ((size_t)t * N + i) * D + k * DD;
        if (m == 0) ((float4*)o)[0] = make_float4(w[0],  w[1],  w[2],  w[3]);
        if (m == 1) ((float4*)o)[1] = make_float4(w[4],  w[5],  w[6],  w[7]);
        if (m == 2) ((float4*)o)[2] = make_float4(w[8],  w[9],  w[10], w[11]);
        if (m == 3) ((float4*)o)[3] = make_float4(w[12], w[13], w[14], w[15]);
    }
#undef LDSQ
}

extern "C" void kernel_launch(void* const* d_in, const int* in_sizes, int n_in,
                              void* d_out, int out_size, void* d_ws, size_t ws_size,
                              hipStream_t stream) {
    const float* x_all = (const float*)d_in[0];
    const int*   nbrs  = (const int*)d_in[1];
    float*       out   = (float*)d_out;

    // one wave per node, 4 waves per block
    const int blocks = (N + 3) / 4;  // 12500
    eaconv_fused<<<blocks, 256, 0, stream>>>(x_all, nbrs, out);
}

// Round 5
// 183.363 us; speedup vs baseline: 1.3834x; 1.3125x over previous
//
#include <hip/hip_runtime.h>

// EAConv: EM-routing neighbor aggregation + temporal blend, fully fused.
// T=3, b=1, n=50000, d=64, m=16, K=4, dd=16.
// R11: VALU-count attack. R10 was VALU-issue-bound (81% busy) because the
// (k,m)-lane layout paid 4 dpp-adds per element per rowsum (3 sweeps x 16
// elems x 4 stages = 192 cross-lane adds/wave-t) for what is 16 MACs of
// real math. New mapping: lane = OUTPUT DIM d=16k+p.
//   - zr[m]  = z[m][d]        (column, 16 regs) -> u-update = 16 serial FMA
//   - zrow[q]= z[p][16k+4q..] (row,    16 regs) -> logit dot for m=p = 16 FMA
//     (dot lands at lane (k,p) = exactly where softmax-over-k wants it)
//   - u, xk, acc are SCALAR per lane now.
//   - cross-lane left: u-row/w-row round trip through wave-private LDS
//     (1 ds_write_b32 + 4 broadcast ds_read_b128 per sweep; LDS pipe, no
//     barrier needed: same-wave DS ops are in-order, compiler emits lgkmcnt)
//   - norms over dd=16 = DPP-row reductions (DPP rows are 16 lanes): 5 ops.
// Gather + XOR-swizzled LDS transpose identical to R10 (verified).
// Store: 1 dword/lane, coalesced 256B/wave. No __syncthreads anywhere.

constexpr int T  = 3;
constexpr int N  = 50000;
constexpr int D  = 64;
constexpr int M  = 16;
constexpr float EPS2 = 1e-24f;  // (1e-12)^2

template <int CTRL>
__device__ __forceinline__ float dpp_add(float v) {
    // mov_dpp with undef old -> GCNDPPCombine fuses into v_add_f32_dpp
    int rot = __builtin_amdgcn_mov_dpp(__float_as_int(v), CTRL, 0xF, 0xF, false);
    return v + __int_as_float(rot);
}
// sum over the 16 lanes of a DPP row; result broadcast within the row
__device__ __forceinline__ float rowsum16(float v) {
    v = dpp_add<0x128>(v);  // row_ror:8
    v = dpp_add<0x124>(v);  // row_ror:4
    v = dpp_add<0x122>(v);  // row_ror:2
    v = dpp_add<0x121>(v);  // row_ror:1
    return v;
}

__global__ __launch_bounds__(256, 4) void eaconv_fused(
    const float* __restrict__ x_all,   // [T,N,D]
    const int*   __restrict__ nbr_all, // [T,N,M]
    float*       __restrict__ out)     // [T,N,D]
{
    __shared__ float zb[4][M * D];     // 4KB/wave: neighbor rows (swizzled)
    __shared__ float ub[4][D];         // 256B/wave: u broadcast row
    __shared__ float wb[4][D];         // 256B/wave: weight broadcast row
    const int wv   = threadIdx.x >> 6;
    const int i    = blockIdx.x * 4 + wv;
    const int lane = threadIdx.x & 63;
    if (i >= N) return;
    const int p  = lane & 15;          // = neighbor index m for lane scalars
    const int k  = lane >> 4;          // factor
    const int x7 = p & 7;
    float* zw = zb[wv];
    float* uw = ub[wv];
    float* wwp = wb[wv];

    // t-invariant address pieces
    const int gq = lane >> 2;          // granule of own dim d=lane
    const int ge = lane & 3;           // elem within granule
    const int c4 = (4 * k) ^ x7;       // zrow granule base (see LDSQ deriv)

    float acc = 0.f;                   // temporal-blend carry (scalar!)
    const float s1q = 0.25f * 0.7310585786300049f;  // 0.25*sigmoid(1)

#pragma unroll
    for (int t = 0; t < T; ++t) {
        const float* x = x_all + (size_t)t * N * D;
        int j = nbr_all[((size_t)t * N + i) * M + p];
        const bool valid = (unsigned)j < (unsigned)N;
        j = valid ? j : 0;

        // ---- coalesced gather (R10-verified): 4 instrs x 4 full rows.
        // lane fetches 16B of row j_{4c+k}, dims [4p..4p+3]; LDS slot p^(row&7)
#pragma unroll
        for (int c = 0; c < 4; ++c) {
            const int mm = 4 * c + k;
            const int jr = __shfl(j, mm, 64);
            const float4 v = *(const float4*)(x + (size_t)jr * D + p * 4);
            *(float4*)&zw[mm * 64 + ((p ^ (mm & 7)) << 2)] = v;
        }

        // ---- own dim: scalar load + DPP-row norm ----
        const float xv = x[(size_t)i * D + lane];
        const float sx = rowsum16(xv * xv);
        const float xh = xv * __builtin_amdgcn_rsqf(fmaxf(sx, EPS2));

        // ---- z row p, factor k (for dots): zrow[4q+e] = z[p][16k+4q+e] ----
        float zrow[16];
#pragma unroll
        for (int q = 0; q < 4; ++q) {
            const float4 v = *(const float4*)&zw[p * 64 + ((c4 ^ q) << 2)];
            zrow[4*q+0] = v.x; zrow[4*q+1] = v.y;
            zrow[4*q+2] = v.z; zrow[4*q+3] = v.w;
        }
        // ---- z column d (for updates): zr[m] = z[m][lane] ----
        // byte: m*256 + ((gq^(m&7))<<4) + ge*4 ; 64 distinct floats -> 2-way
        float zr[16];
#pragma unroll
        for (int m = 0; m < 16; ++m)
            zr[m] = zw[m * 64 + ((gq ^ (m & 7)) << 2) + ge];

        // ---- neighbor norm (per-lane serial over its row): rz[m=p,k] ----
        float s0 = zrow[0]*zrow[0], s1 = zrow[1]*zrow[1],
              s2 = zrow[2]*zrow[2], s3 = zrow[3]*zrow[3];
#pragma unroll
        for (int q = 4; q < 16; q += 4) {
            s0 = fmaf(zrow[q+0], zrow[q+0], s0);
            s1 = fmaf(zrow[q+1], zrow[q+1], s1);
            s2 = fmaf(zrow[q+2], zrow[q+2], s2);
            s3 = fmaf(zrow[q+3], zrow[q+3], s3);
        }
        float rz = __builtin_amdgcn_rsqf(fmaxf((s0+s1)+(s2+s3), EPS2));
        if (!valid) rz = 0.f;

        // ---- iter 0: u = 4*xh + sum_m rz_m * z[m][d]  (direction only) ----
        wwp[k * 16 + p] = rz;          // broadcast rz row through LDS
        float rzr[16];
#pragma unroll
        for (int q = 0; q < 4; ++q) {
            const float4 v = *(const float4*)&wwp[k * 16 + 4 * q];
            rzr[4*q+0] = v.x; rzr[4*q+1] = v.y;
            rzr[4*q+2] = v.z; rzr[4*q+3] = v.w;
        }
        float u = xh * 4.0f;
#pragma unroll
        for (int m = 0; m < 16; ++m) u = fmaf(rzr[m], zr[m], u);
        float inv = __builtin_amdgcn_rsqf(fmaxf(rowsum16(u * u), EPS2));
        uw[lane] = u;

        // ---- iters 1..2 ----
#pragma unroll
        for (int it = 1; it < 3; ++it) {
            // dot[m=p,k] = z-row . u-row (u broadcast through LDS)
            float urow[16];
#pragma unroll
            for (int q = 0; q < 4; ++q) {
                const float4 v = *(const float4*)&uw[k * 16 + 4 * q];
                urow[4*q+0] = v.x; urow[4*q+1] = v.y;
                urow[4*q+2] = v.z; urow[4*q+3] = v.w;
            }
            float d0 = zrow[0]*urow[0], d1 = zrow[1]*urow[1],
                  d2 = zrow[2]*urow[2], d3 = zrow[3]*urow[3];
#pragma unroll
            for (int q = 4; q < 16; q += 4) {
                d0 = fmaf(zrow[q+0], urow[q+0], d0);
                d1 = fmaf(zrow[q+1], urow[q+1], d1);
                d2 = fmaf(zrow[q+2], urow[q+2], d2);
                d3 = fmaf(zrow[q+3], urow[q+3], d3);
            }
            const float dot = (d0 + d1) + (d2 + d3);
            const float logit = dot * (rz * inv);   // zhat.uhat in [-1,1]
            const float e = __expf(logit);
            float es = e + __shfl_xor(e, 16, 64);   // softmax over k
            es += __shfl_xor(es, 32, 64);
            const float wf = e * __builtin_amdgcn_rcpf(es) * rz;

            // broadcast weight row; update = 16 serial FMA on z column
            wwp[k * 16 + p] = wf;
            float wr[16];
#pragma unroll
            for (int q = 0; q < 4; ++q) {
                const float4 v = *(const float4*)&wwp[k * 16 + 4 * q];
                wr[4*q+0] = v.x; wr[4*q+1] = v.y;
                wr[4*q+2] = v.z; wr[4*q+3] = v.w;
            }
            u = xh;
#pragma unroll
            for (int m = 0; m < 16; ++m) u = fmaf(wr[m], zr[m], u);
            if (it < 2) {
                inv = __builtin_amdgcn_rsqf(fmaxf(rowsum16(u * u), EPS2));
                uw[lane] = u;
            }
        }

        // ---- temporal blend (scalar) + coalesced store ----
        float wout;
        if (t == 0)      { wout = u; acc = u; }
        else if (t == 1) { wout = 0.25f * acc + 0.5f * u;
                           acc = fmaf(s1q, wout, 0.125f * acc); }
        else             { wout = acc + 0.5f * u; }
        out[((size_t)t * N + i) * D + lane] = wout;
    }
}

extern "C" void kernel_launch(void* const* d_in, const int* in_sizes, int n_in,
                              void* d_out, int out_size, void* d_ws, size_t ws_size,
                              hipStream_t stream) {
    const float* x_all = (const float*)d_in[0];
    const int*   nbrs  = (const int*)d_in[1];
    float*       out   = (float*)d_out;

    // one wave per node, 4 waves per block
    const int blocks = (N + 3) / 4;  // 12500
    eaconv_fused<<<blocks, 256, 0, stream>>>(x_all, nbrs, out);
}